// Round 2
// baseline (1206.137 us; speedup 1.0000x reference)
//
#include <hip/hip_runtime.h>
#include <math.h>
#include <stdint.h>

namespace {
constexpr int kN = 768, kCT = 768, kCS = 384, kCP = 128, kNH = 16, kHD = 48;
constexpr float kEps = 1e-5f;
constexpr float kQScale = 0.14433756729740643f;  // 1/sqrt(48)
}

typedef __attribute__((ext_vector_type(8))) short short8;
typedef __attribute__((ext_vector_type(4))) float floatx4;

__device__ __forceinline__ float sigf(float x) { return 1.f / (1.f + expf(-x)); }
__device__ __forceinline__ unsigned short f2bf(float x) {  // RNE bf16 round
  uint32_t v = __builtin_bit_cast(uint32_t, x);
  return (unsigned short)((v + 0x7fffu + ((v >> 16) & 1u)) >> 16);
}
__device__ __forceinline__ float bf2f(unsigned short u) {
  uint32_t v = ((uint32_t)u) << 16;
  return __builtin_bit_cast(float, v);
}

#if __has_builtin(__builtin_amdgcn_global_load_lds)
#define HAVE_GLL 1
#define ASYNC_COPY16(gp, lp)                                                     \
  __builtin_amdgcn_global_load_lds((const __attribute__((address_space(1))) void*)(gp), \
                                   (__attribute__((address_space(3))) void*)(lp), 16, 0, 0)
#else
#define HAVE_GLL 0
#endif

// ---------------- coalesced weight transpose -> bf16, 32x32 LDS tiles ---------------------
// All sources are [K][768] fp32 row-major; dst[n*K+k] = bf16(src[k*768+n]).
__global__ __launch_bounds__(256) void transpose_pack_kernel(
    const float* __restrict__ Wg, const float* __restrict__ Wb,
    const float* __restrict__ Wq, const float* __restrict__ Wk,
    const float* __restrict__ Wv, const float* __restrict__ Wgate,
    const float* __restrict__ Wog, const float* __restrict__ Wout,
    unsigned short* __restrict__ p_adaT, unsigned short* __restrict__ p_qkvT,
    unsigned short* __restrict__ WogT, unsigned short* __restrict__ WoutT) {
  __shared__ float tile[32][33];
  // tiles per matrix: K/32 * 24 ; cumulative
  const int cum[8] = {288, 576, 1152, 1728, 2304, 2880, 3168, 3744};
  const int srcK[8] = {384, 384, 768, 768, 768, 768, 384, 768};
  int bid = blockIdx.x;
  int m = 0;
#pragma unroll
  for (int q = 0; q < 8; ++q)
    if (bid >= cum[q]) m = q + 1;
  const int base = m ? cum[m - 1] : 0;
  const int tloc = bid - base;
  const float* src = m == 0 ? Wg : m == 1 ? Wb : m == 2 ? Wq : m == 3 ? Wk
                   : m == 4 ? Wv : m == 5 ? Wgate : m == 6 ? Wog : Wout;
  unsigned short* dst =
      m == 0 ? p_adaT : m == 1 ? (p_adaT + 768 * 384)
    : m == 2 ? p_qkvT : m == 3 ? (p_qkvT + 768 * 768)
    : m == 4 ? (p_qkvT + 2 * 768 * 768) : m == 5 ? (p_qkvT + 3 * 768 * 768)
    : m == 6 ? WogT : WoutT;
  const int K = srcK[m];
  const int bk = tloc / 24, bn = tloc % 24;
  const int k0 = bk * 32, n0 = bn * 32;
  const int tx = threadIdx.x & 31, ty = threadIdx.x >> 5;
#pragma unroll
  for (int r = 0; r < 4; ++r)
    tile[ty + 8 * r][tx] = src[(size_t)(k0 + ty + 8 * r) * 768 + n0 + tx];
  __syncthreads();
#pragma unroll
  for (int r = 0; r < 4; ++r)
    dst[(size_t)(n0 + ty + 8 * r) * K + k0 + tx] = f2bf(tile[tx][ty + 8 * r]);
}

// ---------------- pack (small): fused biases, s->bf16, pairbias precompute ----------------
__global__ __launch_bounds__(256) void pack_kernel(
    const float* __restrict__ bg, const float* __restrict__ bq,
    const float* __restrict__ s, const float* __restrict__ Wpb,
    const float* __restrict__ gamma, const float* __restrict__ beta,
    float* __restrict__ pb_ada, float* __restrict__ pb_qk,
    unsigned short* __restrict__ s_bf, float* __restrict__ gamW,
    float* __restrict__ pairC) {
  const int T1 = 1536;
  const int T2 = T1 + 3072;
  const int T3 = T2 + 1536 * 384;
  const int T4 = T3 + 2048;
  const int T5 = T4 + 32;
  int idx = blockIdx.x * 256 + threadIdx.x;
  if (idx < T1) {
    pb_ada[idx] = (idx < 768) ? bg[idx] : 0.f;
  } else if (idx < T2) {
    int c = idx - T1;
    pb_qk[c] = (c < 768) ? bq[c] : 0.f;
  } else if (idx < T3) {
    int r = idx - T2;
    s_bf[r] = f2bf(s[r]);
  } else if (idx < T4) {  // gamW[c][h] = gamma[c]*Wpb[c][h]
    int r = idx - T3;
    int c = r >> 4, h = r & 15;
    gamW[r] = gamma[c] * Wpb[c * 16 + h];
  } else if (idx < T5) {  // pairC[0:16]=sum_c beta*Wpb, pairC[16:32]=sum_c gamma*Wpb
    int r = idx - T4;
    float acc = 0.f;
    if (r < 16) {
      for (int c = 0; c < 128; ++c) acc += beta[c] * Wpb[c * 16 + r];
      pairC[r] = acc;
    } else {
      int h = r - 16;
      for (int c = 0; c < 128; ++c) acc += gamma[c] * Wpb[c * 16 + h];
      pairC[r] = acc;
    }
  }
}

// ---------------- LayerNorm over last dim (no affine), templated C, fp32 out --------------
template <int C>
__global__ __launch_bounds__(256) void ln_kernel(const float* __restrict__ x,
                                                 float* __restrict__ y) {
  constexpr int NV = (C + 255) / 256;
  const int row = blockIdx.x;
  const float* xr = x + (size_t)row * C;
  float vals[NV];
  float s = 0.f, ss = 0.f;
#pragma unroll
  for (int it = 0; it < NV; ++it) {
    int c = threadIdx.x + it * 256;
    float v = (c < C) ? xr[c] : 0.f;
    vals[it] = v;
    s += v;
    ss = fmaf(v, v, ss);
  }
#pragma unroll
  for (int m = 1; m < 64; m <<= 1) { s += __shfl_xor(s, m); ss += __shfl_xor(ss, m); }
  __shared__ float red[8];
  __shared__ float mb[2];
  const int wid = threadIdx.x >> 6, lane = threadIdx.x & 63;
  if (lane == 0) { red[wid * 2] = s; red[wid * 2 + 1] = ss; }
  __syncthreads();
  if (threadIdx.x == 0) {
    float S = red[0] + red[2] + red[4] + red[6];
    float SS = red[1] + red[3] + red[5] + red[7];
    float mean = S / C;
    float var = SS / C - mean * mean;
    mb[0] = mean;
    mb[1] = rsqrtf(var + kEps);
  }
  __syncthreads();
  const float mean = mb[0], rs = mb[1];
#pragma unroll
  for (int it = 0; it < NV; ++it) {
    int c = threadIdx.x + it * 256;
    if (c < C) y[(size_t)row * C + c] = (vals[it] - mean) * rs;
  }
}

// ---------------- LayerNorm, templated C, bf16 out ---------------------------------------
template <int C>
__global__ __launch_bounds__(256) void ln_bf_kernel(const float* __restrict__ x,
                                                    unsigned short* __restrict__ y) {
  constexpr int NV = (C + 255) / 256;
  const int row = blockIdx.x;
  const float* xr = x + (size_t)row * C;
  float vals[NV];
  float s = 0.f, ss = 0.f;
#pragma unroll
  for (int it = 0; it < NV; ++it) {
    int c = threadIdx.x + it * 256;
    float v = (c < C) ? xr[c] : 0.f;
    vals[it] = v;
    s += v;
    ss = fmaf(v, v, ss);
  }
#pragma unroll
  for (int m = 1; m < 64; m <<= 1) { s += __shfl_xor(s, m); ss += __shfl_xor(ss, m); }
  __shared__ float red[8];
  __shared__ float mb[2];
  const int wid = threadIdx.x >> 6, lane = threadIdx.x & 63;
  if (lane == 0) { red[wid * 2] = s; red[wid * 2 + 1] = ss; }
  __syncthreads();
  if (threadIdx.x == 0) {
    float S = red[0] + red[2] + red[4] + red[6];
    float SS = red[1] + red[3] + red[5] + red[7];
    float mean = S / C;
    float var = SS / C - mean * mean;
    mb[0] = mean;
    mb[1] = rsqrtf(var + kEps);
  }
  __syncthreads();
  const float mean = mb[0], rs = mb[1];
#pragma unroll
  for (int it = 0; it < NV; ++it) {
    int c = threadIdx.x + it * 256;
    if (c < C) y[(size_t)row * C + c] = f2bf((vals[it] - mean) * rs);
  }
}

// ---------------- a_norm = sigmoid(G)*a_ln + Bv  -> bf16 ---------------------------------
__global__ __launch_bounds__(256) void anorm_kernel(const float* __restrict__ gb,
                                                    const float* __restrict__ a_ln,
                                                    unsigned short* __restrict__ a_norm) {
  int idx = blockIdx.x * 256 + threadIdx.x;  // < 1536*768
  int row = idx / kCT, col = idx % kCT;
  float g = gb[(size_t)row * (2 * kCT) + col];
  float bv = gb[(size_t)row * (2 * kCT) + kCT + col];
  a_norm[idx] = f2bf(sigf(g) * a_ln[idx] + bv);
}

// ---------------- bf16 MFMA GEMM: C[M,N] = A[M,K] @ Wt[N,K]^T, fp32 out -------------------
// BMx128 tile (BM=128 or 64), BK=32, 4 waves, 16x16x32 MFMA, XOR-swizzled LDS,
// global_load_lds width 16. Epilogue: +bias[col], sigmoid col>=sig_start, *aux[row,col].
template <int BM>
__global__ __launch_bounds__(256) void gemm_bf_kernel(
    const unsigned short* __restrict__ A, const unsigned short* __restrict__ Wt,
    const float* __restrict__ bias, const float* __restrict__ aux,
    float* __restrict__ C, int M, int Nn, int K, int sig_start) {
  constexpr int TM = BM / 32;  // 4 (BM=128) or 2 (BM=64)
  __shared__ __align__(16) unsigned short As[BM * 32];
  __shared__ __align__(16) unsigned short Bs[128 * 32];
  const int t = threadIdx.x;
  const int wid = t >> 6, lane = t & 63;
  const int quad = lane >> 4, m16 = lane & 15;
  const int wm = (wid >> 1) * (BM / 2), wn = (wid & 1) * 64;
  const int bm = blockIdx.y * BM, bn = blockIdx.x * 128;
  const int swz = quad ^ ((m16 >> 1) & 3);
  // staging: chunk ci holds (row=ci>>2, kchunk=(ci&3)^((row>>1)&3)) of this k0-slab
  const int ci0 = t, ci1 = t + 256;
  const int am0 = ci0 >> 2, ak0 = ((ci0 & 3) ^ ((am0 >> 1) & 3)) * 8;
  const int am1 = ci1 >> 2, ak1 = ((ci1 & 3) ^ ((am1 >> 1) & 3)) * 8;
  const unsigned short* ga0 = A + (size_t)(bm + am0) * K + ak0;
  const unsigned short* ga1 = A + (size_t)(bm + am1) * K + ak1;  // BM==128 only
  const unsigned short* gw0 = Wt + (size_t)(bn + am0) * K + ak0;
  const unsigned short* gw1 = Wt + (size_t)(bn + am1) * K + ak1;
  floatx4 acc[TM][4] = {};
  for (int k0 = 0; k0 < K; k0 += 32) {
    __syncthreads();
#if HAVE_GLL
    ASYNC_COPY16(ga0 + k0, &As[ci0 * 8]);
    if constexpr (BM == 128) ASYNC_COPY16(ga1 + k0, &As[ci1 * 8]);
    ASYNC_COPY16(gw0 + k0, &Bs[ci0 * 8]);
    ASYNC_COPY16(gw1 + k0, &Bs[ci1 * 8]);
#else
    short8 ra0 = *(const short8*)(ga0 + k0);
    short8 rw0 = *(const short8*)(gw0 + k0);
    short8 rw1 = *(const short8*)(gw1 + k0);
    *(short8*)&As[ci0 * 8] = ra0;
    if constexpr (BM == 128) {
      short8 ra1 = *(const short8*)(ga1 + k0);
      *(short8*)&As[ci1 * 8] = ra1;
    }
    *(short8*)&Bs[ci0 * 8] = rw0;
    *(short8*)&Bs[ci1 * 8] = rw1;
#endif
    __syncthreads();
    short8 af[TM], bfv[4];
#pragma unroll
    for (int tm = 0; tm < TM; ++tm)
      af[tm] = *(const short8*)&As[(wm + tm * 16 + m16) * 32 + swz * 8];
#pragma unroll
    for (int tn = 0; tn < 4; ++tn)
      bfv[tn] = *(const short8*)&Bs[(wn + tn * 16 + m16) * 32 + swz * 8];
#pragma unroll
    for (int tm = 0; tm < TM; ++tm)
#pragma unroll
      for (int tn = 0; tn < 4; ++tn)
        acc[tm][tn] = __builtin_amdgcn_mfma_f32_16x16x32_bf16(af[tm], bfv[tn], acc[tm][tn], 0, 0, 0);
  }
  // epilogue: C/D layout col=lane&15, row=quad*4+reg
#pragma unroll
  for (int tm = 0; tm < TM; ++tm) {
    const int row0 = bm + wm + tm * 16 + quad * 4;
#pragma unroll
    for (int tn = 0; tn < 4; ++tn) {
      const int col = bn + wn + tn * 16 + m16;
      const float badd = bias ? bias[col] : 0.f;
#pragma unroll
      for (int r = 0; r < 4; ++r) {
        float v = acc[tm][tn][r] + badd;
        if (col >= sig_start) v = sigf(v);
        if (aux) v *= aux[(size_t)(row0 + r) * Nn + col];
        C[(size_t)(row0 + r) * Nn + col] = v;
      }
    }
  }
}

// ---------------- pair bias v3: thread-per-j, LN folded into weights, bf16 out ------------
// gamW/pairC read directly from global with wave-uniform indices -> scalar (s_load) path,
// no LDS, no barrier. pb[b,h,i,j] = rs*(dot - mean*gwsum[h]) + constB[h] + mask[b,i,j]
__global__ __launch_bounds__(256) void pairbias2_kernel(
    const float* __restrict__ z, const float* __restrict__ mask,
    const float* __restrict__ gamW, const float* __restrict__ pairC,
    unsigned short* __restrict__ pb) {
  const int t = threadIdx.x;
  const int b = blockIdx.z, i = blockIdx.y;
  const int j = blockIdx.x * 256 + t;
  const float4* __restrict__ zr = (const float4*)&z[((size_t)(b * kN + i) * kN + j) * kCP];
  const float4* __restrict__ gw = (const float4*)gamW;  // [128 c][4 quads of 4 h]
  float sum = 0.f, ss = 0.f;
  floatx4 acc[4] = {};
#pragma unroll 4
  for (int c4 = 0; c4 < 32; ++c4) {  // 4 channels per iteration
    const float4 v = zr[c4];
#pragma unroll
    for (int u = 0; u < 4; ++u) {
      const float vv = (u == 0) ? v.x : (u == 1) ? v.y : (u == 2) ? v.z : v.w;
      sum += vv;
      ss = fmaf(vv, vv, ss);
      const int c = c4 * 4 + u;
#pragma unroll
      for (int q = 0; q < 4; ++q) {
        const float4 g = gw[c * 4 + q];  // uniform address -> SGPR broadcast
        acc[q][0] = fmaf(vv, g.x, acc[q][0]);
        acc[q][1] = fmaf(vv, g.y, acc[q][1]);
        acc[q][2] = fmaf(vv, g.z, acc[q][2]);
        acc[q][3] = fmaf(vv, g.w, acc[q][3]);
      }
    }
  }
  const float mean = sum * (1.f / 128.f);
  const float var = ss * (1.f / 128.f) - mean * mean;
  const float rs = rsqrtf(var + kEps);
  const float mk = mask[(size_t)(b * kN + i) * kN + j];
  const size_t pbase = ((size_t)(b * kNH) * kN + i) * kN + j;
#pragma unroll
  for (int h = 0; h < 16; ++h) {
    const float a = acc[h >> 2][h & 3];
    const float res = fmaf(rs, fmaf(-mean, pairC[16 + h], a), pairC[h]) + mk;
    pb[pbase + (size_t)h * kN * kN] = f2bf(res);  // coalesced: lane=j
  }
}

// ---------------- attention: per-wave (b,h,i); 16 waves/block share k/v LDS tiles ---------
// k/v staged once per 16 query rows with register prefetch of the next chunk overlapping
// the current chunk's compute.
__global__ __launch_bounds__(1024) void attn_kernel(
    const float* __restrict__ qkvg, const unsigned short* __restrict__ pb,
    unsigned short* __restrict__ o_out) {
  __shared__ float kt[64 * 52];
  __shared__ float vt[64 * 52];
  __shared__ float qs[16][48];
  const int b = blockIdx.z, h = blockIdx.y;
  const int t = threadIdx.x, wid = t >> 6, lane = t & 63;
  const int i = blockIdx.x * 16 + wid;
  const size_t rowi = (size_t)(b * kN + i) * (4 * kCT);
  if (lane < 12) {
    float4 q4 = *(const float4*)&qkvg[rowi + h * kHD + lane * 4];
    qs[wid][lane * 4 + 0] = q4.x * kQScale;
    qs[wid][lane * 4 + 1] = q4.y * kQScale;
    qs[wid][lane * 4 + 2] = q4.z * kQScale;
    qs[wid][lane * 4 + 3] = q4.w * kQScale;
  }
  // loader role: threads [0,768) each own one (jl,d4) float4 of k and of v per chunk
  const int jl = t / 12, d4 = t % 12;
  const bool loader = (t < 768);
  float4 kreg, vreg;
  if (loader) {
    const size_t rowj = (size_t)(b * kN + jl) * (4 * kCT);
    kreg = *(const float4*)&qkvg[rowj + kCT + h * kHD + d4 * 4];
    vreg = *(const float4*)&qkvg[rowj + 2 * kCT + h * kHD + d4 * 4];
  }
  float o[48];
#pragma unroll
  for (int d = 0; d < 48; ++d) o[d] = 0.f;
  float mrun = -INFINITY, lsum = 0.f;
  const unsigned short* pbrow = &pb[((size_t)(b * kNH + h) * kN + i) * kN];
  for (int c = 0; c < 12; ++c) {
    __syncthreads();  // previous chunk's consumers done
    if (loader) {
      *(float4*)&kt[jl * 52 + d4 * 4] = kreg;
      *(float4*)&vt[jl * 52 + d4 * 4] = vreg;
    }
    __syncthreads();
    if (loader && c < 11) {  // prefetch next chunk; latency hides under compute below
      const size_t rowj = (size_t)(b * kN + (c + 1) * 64 + jl) * (4 * kCT);
      kreg = *(const float4*)&qkvg[rowj + kCT + h * kHD + d4 * 4];
      vreg = *(const float4*)&qkvg[rowj + 2 * kCT + h * kHD + d4 * 4];
    }
    // logit with 4 independent accumulator chains
    float l0 = bf2f(pbrow[c * 64 + lane]), l1 = 0.f, l2 = 0.f, l3 = 0.f;
#pragma unroll
    for (int d4i = 0; d4i < 12; ++d4i) {
      float4 kk = *(const float4*)&kt[lane * 52 + d4i * 4];
      float4 qq = *(const float4*)&qs[wid][d4i * 4];
      l0 = fmaf(qq.x, kk.x, l0);
      l1 = fmaf(qq.y, kk.y, l1);
      l2 = fmaf(qq.z, kk.z, l2);
      l3 = fmaf(qq.w, kk.w, l3);
    }
    float logit = (l0 + l1) + (l2 + l3);
    float mx = logit;
#pragma unroll
    for (int m = 1; m < 64; m <<= 1) mx = fmaxf(mx, __shfl_xor(mx, m));
    const float mnew = fmaxf(mrun, mx);
    const float alpha = expf(mrun - mnew);
    const float p = expf(logit - mnew);
    lsum = fmaf(lsum, alpha, p);
#pragma unroll
    for (int d4i = 0; d4i < 12; ++d4i) {
      float4 vv = *(const float4*)&vt[lane * 52 + d4i * 4];
      o[d4i * 4 + 0] = fmaf(o[d4i * 4 + 0], alpha, p * vv.x);
      o[d4i * 4 + 1] = fmaf(o[d4i * 4 + 1], alpha, p * vv.y);
      o[d4i * 4 + 2] = fmaf(o[d4i * 4 + 2], alpha, p * vv.z);
      o[d4i * 4 + 3] = fmaf(o[d4i * 4 + 3], alpha, p * vv.w);
    }
    mrun = mnew;
  }
#pragma unroll
  for (int m = 1; m < 64; m <<= 1) lsum += __shfl_xor(lsum, m);
#pragma unroll
  for (int d = 0; d < 48; ++d) {
#pragma unroll
    for (int m = 1; m < 64; m <<= 1) o[d] += __shfl_xor(o[d], m);
  }
  if (lane == 0) {
    const float inv = 1.f / lsum;
    unsigned short* orow = o_out + (size_t)(b * kN + i) * kCT + h * kHD;
#pragma unroll
    for (int d4i = 0; d4i < 12; ++d4i) {
      float4 g4 = *(const float4*)&qkvg[rowi + 3 * kCT + h * kHD + d4i * 4];
      uint32_t u0 = (uint32_t)f2bf(g4.x * o[d4i * 4 + 0] * inv) |
                    ((uint32_t)f2bf(g4.y * o[d4i * 4 + 1] * inv) << 16);
      uint32_t u1 = (uint32_t)f2bf(g4.z * o[d4i * 4 + 2] * inv) |
                    ((uint32_t)f2bf(g4.w * o[d4i * 4 + 3] * inv) << 16);
      *(uint32_t*)&orow[d4i * 4 + 0] = u0;
      *(uint32_t*)&orow[d4i * 4 + 2] = u1;
    }
  }
}

// ==========================================================================================
extern "C" void kernel_launch(void* const* d_in, const int* in_sizes, int n_in,
                              void* d_out, int out_size, void* d_ws, size_t ws_size,
                              hipStream_t stream) {
  const float* a      = (const float*)d_in[0];
  const float* s      = (const float*)d_in[1];
  const float* z      = (const float*)d_in[2];
  const float* mask   = (const float*)d_in[3];
  const float* Wg_ada = (const float*)d_in[4];
  const float* bg_ada = (const float*)d_in[5];
  const float* Wb_ada = (const float*)d_in[6];
  const float* Wq     = (const float*)d_in[7];
  const float* bq     = (const float*)d_in[8];
  const float* Wk     = (const float*)d_in[9];
  const float* Wv     = (const float*)d_in[10];
  const float* Wpb    = (const float*)d_in[11];
  const float* pn_g   = (const float*)d_in[12];
  const float* pn_b   = (const float*)d_in[13];
  const float* Wgate  = (const float*)d_in[14];
  const float* Wout   = (const float*)d_in[15];
  const float* Wog    = (const float*)d_in[16];
  const float* bog    = (const float*)d_in[17];
  float* out = (float*)d_out;

  char* p = (char*)d_ws;
  auto alloc = [&](size_t bytes) -> char* {
    char* r = p;
    p += (bytes + 255) & ~(size_t)255;
    return r;
  };
  float* a_ln  = (float*)alloc((size_t)1536 * 768 * 4);
  float* gb    = (float*)alloc((size_t)1536 * 1536 * 4);
  float* qkvg  = (float*)alloc((size_t)1536 * 3072 * 4);
  float* ogate = (float*)alloc((size_t)1536 * 768 * 4);
  unsigned short* s_ln   = (unsigned short*)alloc((size_t)1536 * 384 * 2);
  unsigned short* a_nrm  = (unsigned short*)alloc((size_t)1536 * 768 * 2);
  unsigned short* s_bf   = (unsigned short*)alloc((size_t)1536 * 384 * 2);
  unsigned short* o_g    = (unsigned short*)alloc((size_t)1536 * 768 * 2);
  unsigned short* pbias  = (unsigned short*)alloc((size_t)2 * 16 * 768 * 768 * 2);
  unsigned short* p_adaT = (unsigned short*)alloc((size_t)1536 * 384 * 2);
  unsigned short* p_qkvT = (unsigned short*)alloc((size_t)3072 * 768 * 2);
  unsigned short* WogT   = (unsigned short*)alloc((size_t)768 * 384 * 2);
  unsigned short* WoutT  = (unsigned short*)alloc((size_t)768 * 768 * 2);
  float* pb_ada = (float*)alloc(1536 * 4);
  float* pb_qk  = (float*)alloc(3072 * 4);
  float* gamW   = (float*)alloc(2048 * 4);
  float* pairC  = (float*)alloc(32 * 4);

  transpose_pack_kernel<<<dim3(3744), 256, 0, stream>>>(
      Wg_ada, Wb_ada, Wq, Wk, Wv, Wgate, Wog, Wout, p_adaT, p_qkvT, WogT, WoutT);
  const int packTot = 1536 + 3072 + 1536 * 384 + 2048 + 32;
  pack_kernel<<<dim3((packTot + 255) / 256), 256, 0, stream>>>(
      bg_ada, bq, s, Wpb, pn_g, pn_b, pb_ada, pb_qk, s_bf, gamW, pairC);
  ln_kernel<768><<<dim3(1536), 256, 0, stream>>>(a, a_ln);
  ln_bf_kernel<384><<<dim3(1536), 256, 0, stream>>>(s, s_ln);
  // gb = [ s_ln@Wg_ada + bg | s_ln@Wb_ada ]
  gemm_bf_kernel<64><<<dim3(12, 24), 256, 0, stream>>>(
      s_ln, p_adaT, pb_ada, nullptr, gb, 1536, 1536, 384, 1 << 30);
  anorm_kernel<<<dim3(1536 * 768 / 256), 256, 0, stream>>>(gb, a_ln, a_nrm);
  // qkvg = a_norm @ [Wq|Wk|Wv|Wgate] (+bq on q, sigmoid on gate cols)
  gemm_bf_kernel<128><<<dim3(24, 12), 256, 0, stream>>>(
      a_nrm, p_qkvT, pb_qk, nullptr, qkvg, 1536, 3072, 768, 2304);
  // ogate = sigmoid(s @ Wog + bog)
  gemm_bf_kernel<64><<<dim3(6, 24), 256, 0, stream>>>(
      s_bf, WogT, bog, nullptr, ogate, 1536, 768, 384, 0);
  pairbias2_kernel<<<dim3(3, 768, 2), 256, 0, stream>>>(z, mask, gamW, pairC, pbias);
  attn_kernel<<<dim3(48, 16, 2), 1024, 0, stream>>>(qkvg, pbias, o_g);
  // out = ogate * (o_g @ Wout)
  gemm_bf_kernel<64><<<dim3(6, 24), 256, 0, stream>>>(
      o_g, WoutT, nullptr, ogate, out, 1536, 768, 768, 1 << 30);
}